// Round 1
// baseline (123.982 us; speedup 1.0000x reference)
//
#include <hip/hip_runtime.h>

// Problem constants (inputs: [B=64, T=256, D=1024] f32)
#define B_DIM 64
#define T_STEPS 256
#define D_DIM 1024
#define UNROLL 16   // timesteps prefetched per chunk (4KB/wave in flight)

// Switch: 1 = FMA-form polynomial (Eigen pmadd / contracted), 0 = separate mul+add
#define USE_FMA_POLY 1

// XLA/Eigen f32 tanh rational approximation — must match the reference's
// jnp.tanh bit-for-bit or accumulated-v threshold crossings can flip.
__device__ __forceinline__ float xla_tanhf(float x) {
    const float kClamp = 7.90531110763549805f;
    float xc = fminf(fmaxf(x, -kClamp), kClamp);
    float x2 = xc * xc;
#if USE_FMA_POLY
    float p = __builtin_fmaf(x2, -2.76076847742355e-16f, 2.00018790482477e-13f);
    p = __builtin_fmaf(x2, p, -8.60467152213735e-11f);
    p = __builtin_fmaf(x2, p, 5.12229709037114e-08f);
    p = __builtin_fmaf(x2, p, 1.48572235717979e-05f);
    p = __builtin_fmaf(x2, p, 6.37261928875436e-04f);
    p = __builtin_fmaf(x2, p, 4.89352455891786e-03f);
    p = xc * p;
    float q = __builtin_fmaf(x2, 1.19825839466702e-06f, 1.18534705686654e-04f);
    q = __builtin_fmaf(x2, q, 2.26843463243900e-03f);
    q = __builtin_fmaf(x2, q, 4.89352518554385e-03f);
#else
    float p = __fadd_rn(__fmul_rn(x2, -2.76076847742355e-16f), 2.00018790482477e-13f);
    p = __fadd_rn(__fmul_rn(x2, p), -8.60467152213735e-11f);
    p = __fadd_rn(__fmul_rn(x2, p), 5.12229709037114e-08f);
    p = __fadd_rn(__fmul_rn(x2, p), 1.48572235717979e-05f);
    p = __fadd_rn(__fmul_rn(x2, p), 6.37261928875436e-04f);
    p = __fadd_rn(__fmul_rn(x2, p), 4.89352455891786e-03f);
    p = __fmul_rn(xc, p);
    float q = __fadd_rn(__fmul_rn(x2, 1.19825839466702e-06f), 1.18534705686654e-04f);
    q = __fadd_rn(__fmul_rn(x2, q), 2.26843463243900e-03f);
    q = __fadd_rn(__fmul_rn(x2, q), 4.89352518554385e-03f);
#endif
    float r = p / q;           // IEEE divide (no fast-math in harness build)
    return (fabsf(x) < 0.0004f) ? x : r;
}

// One thread per (b, d) sequence; serial over T with 16-deep register
// prefetch for memory-level parallelism (only 4 waves/CU are resident,
// so ILP is the latency-hiding mechanism).
__global__ __launch_bounds__(256)
void spike_scan_kernel(const float* __restrict__ in, float* __restrict__ out) {
    const int gid = blockIdx.x * blockDim.x + threadIdx.x;   // 0..65535
    const int b = gid >> 10;            // / D_DIM
    const int d = gid & (D_DIM - 1);    // % D_DIM
    const long base = (long)b * (T_STEPS * D_DIM) + d;
    const float* ip = in + base;
    float* op = out + base;

    float v = 0.0f;
    float x[UNROLL], xn[UNROLL];

    // prime chunk 0
    #pragma unroll
    for (int u = 0; u < UNROLL; ++u) x[u] = ip[u * D_DIM];

    constexpr int CHUNKS = T_STEPS / UNROLL;
    for (int c = 0; c < CHUNKS; ++c) {
        const float* ipc = ip + (c + 1) * UNROLL * D_DIM;
        float* opc = op + c * UNROLL * D_DIM;

        if (c + 1 < CHUNKS) {
            #pragma unroll
            for (int u = 0; u < UNROLL; ++u) xn[u] = ipc[u * D_DIM];
        }

        #pragma unroll
        for (int u = 0; u < UNROLL; ++u) {
            float r = xla_tanhf(x[u]);
#if USE_FMA_POLY
            v = __builtin_fmaf(r, 0.01f, v);        // v += r*DT
#else
            v = __fadd_rn(v, __fmul_rn(r, 0.01f));
#endif
            float sp = (v >= 1.0f)  ? 1.0f : 0.0f;
            float sn = (v <= -1.0f) ? 1.0f : 0.0f;
            v = (v - sp) + sn;                      // subtractive reset (exact fp ops)
            opc[u * D_DIM] = (sp - sn) * 100.0f;    // (sp-sn)/0.01f == ±100.0f exactly
        }

        #pragma unroll
        for (int u = 0; u < UNROLL; ++u) x[u] = xn[u];
    }
}

extern "C" void kernel_launch(void* const* d_in, const int* in_sizes, int n_in,
                              void* d_out, int out_size, void* d_ws, size_t ws_size,
                              hipStream_t stream) {
    const float* in = (const float*)d_in[0];
    float* out = (float*)d_out;
    const int total = B_DIM * D_DIM;          // 65536 threads, one per sequence
    dim3 block(256);
    dim3 grid(total / 256);                   // 256 blocks -> ~1 block/CU
    spike_scan_kernel<<<grid, block, 0, stream>>>(in, out);
}

// Round 2
// 115.232 us; speedup vs baseline: 1.0759x; 1.0759x over previous
//
#include <hip/hip_runtime.h>

// Problem: inputs [B=64, T=256, D=1024] f32; tanh -> sequential dual-threshold
// integrate-and-fire scan over T per (b,d). 65536 independent sequences
// -> 1024 waves -> 4 waves/CU (structural; scan is order-dependent, no
// parallel scan over T). Latency hiding must come from async DMA, not TLP.
#define B_DIM 64
#define T_STEPS 256
#define D_DIM 1024
#define CT 32                  // timesteps per LDS chunk
#define CHUNKS (T_STEPS / CT)  // 8
#define TPB 256

typedef __attribute__((address_space(3))) void lds_void;
typedef __attribute__((address_space(1))) const void glob_void;

// XLA/Eigen f32 tanh rational approximation — bit-exact vs jnp.tanh
// (verified round 1: absmax = 0.0). DO NOT change the FMA structure.
__device__ __forceinline__ float xla_tanhf(float x) {
    const float kClamp = 7.90531110763549805f;
    float xc = fminf(fmaxf(x, -kClamp), kClamp);
    float x2 = xc * xc;
    float p = __builtin_fmaf(x2, -2.76076847742355e-16f, 2.00018790482477e-13f);
    p = __builtin_fmaf(x2, p, -8.60467152213735e-11f);
    p = __builtin_fmaf(x2, p, 5.12229709037114e-08f);
    p = __builtin_fmaf(x2, p, 1.48572235717979e-05f);
    p = __builtin_fmaf(x2, p, 6.37261928875436e-04f);
    p = __builtin_fmaf(x2, p, 4.89352455891786e-03f);
    p = xc * p;
    float q = __builtin_fmaf(x2, 1.19825839466702e-06f, 1.18534705686654e-04f);
    q = __builtin_fmaf(x2, q, 2.26843463243900e-03f);
    q = __builtin_fmaf(x2, q, 4.89352518554385e-03f);
    float r = p / q;           // IEEE divide — required for bit-exactness
    return (fabsf(x) < 0.0004f) ? x : r;
}

// One block per (b, 256-wide d-slice). Double-buffered async global->LDS
// staging of 32-timestep chunks; one barrier per chunk (m97 pattern: DMA for
// chunk c+1 issues right after the barrier, overlapping compute of chunk c).
__global__ __launch_bounds__(TPB, 1)
void spike_scan_kernel(const float* __restrict__ in, float* __restrict__ out) {
    __shared__ float buf[2][CT][TPB];   // 2 x 32 KB = 64 KB (1 block/CU)

    const int tid = threadIdx.x;
    const int blk = blockIdx.x;          // 0..255
    const int b   = blk >> 2;            // blk / 4
    const int d0  = (blk & 3) << 8;      // (blk % 4) * 256
    const size_t base = (size_t)b * (T_STEPS * D_DIM) + d0;
    const float* ip = in + base;         // row t: ip + t*D_DIM, 256 floats
    float* op = out + base + tid;

    const int wave = tid >> 6;           // 0..3
    const int lane = tid & 63;

    // Stage chunk c into buf[pp]: each wave DMAs 8 rows; one width-16
    // global_load_lds covers a full 256-float row (lane scatter = 16*lane
    // bytes, matching the row-contiguous LDS layout — no padding allowed).
    auto stage = [&](int c, int pp) {
        const float* g0 = ip + (size_t)(c * CT + wave * 8) * D_DIM + lane * 4;
        #pragma unroll
        for (int r = 0; r < 8; ++r) {
            __builtin_amdgcn_global_load_lds(
                (glob_void*)(g0 + (size_t)r * D_DIM),
                (lds_void*)&buf[pp][wave * 8 + r][0],
                16, 0, 0);
        }
    };

    stage(0, 0);
    float v = 0.0f;

    for (int c = 0; c < CHUNKS; ++c) {
        const int pp = c & 1;
        __syncthreads();                 // drains own DMA (vmcnt 0) + barrier:
                                         // buf[pp] now fully staged block-wide
        if (c + 1 < CHUNKS) stage(c + 1, pp ^ 1);   // overlaps compute below

        float* opc = op + (size_t)c * CT * D_DIM;
        #pragma unroll
        for (int u = 0; u < CT; ++u) {
            float r = xla_tanhf(buf[pp][u][tid]);   // stride-4B: 2 lanes/bank, free
            v = __builtin_fmaf(r, 0.01f, v);        // v += r*DT
            float sp = (v >= 1.0f)  ? 1.0f : 0.0f;
            float sn = (v <= -1.0f) ? 1.0f : 0.0f;
            v = (v - sp) + sn;                      // subtractive reset (exact)
            // (sp-sn)/0.01 == ±100.0f exactly; nt store keeps input L3-resident
            __builtin_nontemporal_store((sp - sn) * 100.0f, opc + (size_t)u * D_DIM);
        }
    }
}

extern "C" void kernel_launch(void* const* d_in, const int* in_sizes, int n_in,
                              void* d_out, int out_size, void* d_ws, size_t ws_size,
                              hipStream_t stream) {
    const float* in = (const float*)d_in[0];
    float* out = (float*)d_out;
    dim3 block(TPB);
    dim3 grid(B_DIM * (D_DIM / TPB));   // 256 blocks -> 1 per CU
    spike_scan_kernel<<<grid, block, 0, stream>>>(in, out);
}

// Round 3
// 112.174 us; speedup vs baseline: 1.1053x; 1.0273x over previous
//
#include <hip/hip_runtime.h>
#include <stdint.h>

// inputs [B=64, T=256, D=1024] f32; tanh -> sequential dual-threshold
// integrate-and-fire scan over T per (b,d). 65536 sequences = 1024 waves
// = 4 waves/CU (structural). Latency hiding: register double-buffer with
// raw asm global loads + manual s_waitcnt vmcnt(N) that NEVER drains to 0
// (AITER-style pipeline; compiler-invisible memory ops).
#define B_DIM 64
#define T_STEPS 256
#define D_DIM 1024
#define CT 16                   // timesteps per register chunk
#define CHUNKS (T_STEPS / CT)   // 16
#define TPB 256

// XLA/Eigen f32 tanh rational approximation — bit-exact vs jnp.tanh
// (verified rounds 1-2: absmax = 0.0). DO NOT change the FMA structure.
__device__ __forceinline__ float xla_tanhf(float x) {
    const float kClamp = 7.90531110763549805f;
    float xc = fminf(fmaxf(x, -kClamp), kClamp);
    float x2 = xc * xc;
    float p = __builtin_fmaf(x2, -2.76076847742355e-16f, 2.00018790482477e-13f);
    p = __builtin_fmaf(x2, p, -8.60467152213735e-11f);
    p = __builtin_fmaf(x2, p, 5.12229709037114e-08f);
    p = __builtin_fmaf(x2, p, 1.48572235717979e-05f);
    p = __builtin_fmaf(x2, p, 6.37261928875436e-04f);
    p = __builtin_fmaf(x2, p, 4.89352455891786e-03f);
    p = xc * p;
    float q = __builtin_fmaf(x2, 1.19825839466702e-06f, 1.18534705686654e-04f);
    q = __builtin_fmaf(x2, q, 2.26843463243900e-03f);
    q = __builtin_fmaf(x2, q, 4.89352518554385e-03f);
    float r = p / q;           // IEEE divide — required for bit-exactness
    return (fabsf(x) < 0.0004f) ? x : r;
}

// --- raw-asm pipeline building blocks -----------------------------------
// One load + advance voff by one timestep (D_DIM*4 = 4096 B). saddr form:
// addr = SGPR base + zext(voff); whole tensor is 64 MB so 32-bit offsets fit.
#define LD(i) "global_load_dword %" #i ", %16, %17\n\t" \
              "v_add_u32 %16, 0x1000, %16\n\t"

// Issue 16 loads for one chunk into buffer B (compiler never sees them as
// memory ops -> no auto-waitcnt; vmcnt tracked manually).
#define ISSUE16(B) asm volatile( \
    LD(0) LD(1) LD(2) LD(3) LD(4) LD(5) LD(6) LD(7) \
    LD(8) LD(9) LD(10) LD(11) LD(12) LD(13) LD(14) LD(15) \
    : "=v"(B[0]), "=v"(B[1]), "=v"(B[2]), "=v"(B[3]), \
      "=v"(B[4]), "=v"(B[5]), "=v"(B[6]), "=v"(B[7]), \
      "=v"(B[8]), "=v"(B[9]), "=v"(B[10]), "=v"(B[11]), \
      "=v"(B[12]), "=v"(B[13]), "=v"(B[14]), "=v"(B[15]), \
      "+v"(voffi) \
    : "s"(inp_u) : "memory")

// Wait until <= CNT vmem ops outstanding; "+v" on all 16 regs of the buffer
// we're about to read makes every use data-dependent on this wait (stops
// the scheduler hoisting tanh above it).
#define WAITBUF(B, CNT) asm volatile("s_waitcnt vmcnt(" CNT ")" \
    : "+v"(B[0]), "+v"(B[1]), "+v"(B[2]), "+v"(B[3]), \
      "+v"(B[4]), "+v"(B[5]), "+v"(B[6]), "+v"(B[7]), \
      "+v"(B[8]), "+v"(B[9]), "+v"(B[10]), "+v"(B[11]), \
      "+v"(B[12]), "+v"(B[13]), "+v"(B[14]), "+v"(B[15]) \
    :: "memory")

// 16 scan steps + 16 nontemporal stores (stores count toward vmcnt in
// issue order — accounted for in the WAITBUF constants).
#define COMPUTE16(B) \
    _Pragma("unroll") \
    for (int u = 0; u < CT; ++u) { \
        float r = xla_tanhf(B[u]); \
        v = __builtin_fmaf(r, 0.01f, v); \
        float sp = (v >= 1.0f)  ? 1.0f : 0.0f; \
        float sn = (v <= -1.0f) ? 1.0f : 0.0f; \
        v = (v - sp) + sn; \
        float o = (sp - sn) * 100.0f; \
        asm volatile("global_store_dword %0, %1, %2 nt\n\t" \
                     "v_add_u32 %0, 0x1000, %0" \
                     : "+v"(voffo) : "v"(o), "s"(outp_u) : "memory"); \
    }

// Steady-state chunk c: issue L(c+1); newest 32 vmem ops = 16 stores of
// chunk c-1 + 16 loads of chunk c+1 -> vmcnt(32) guarantees L(c) retired.
#define CHUNK_MID(CUR, NXT) do { ISSUE16(NXT); WAITBUF(CUR, "32"); COMPUTE16(CUR); } while (0)

__global__ __launch_bounds__(TPB)
void spike_scan_kernel(const float* __restrict__ in, float* __restrict__ out) {
    const int gid = blockIdx.x * blockDim.x + threadIdx.x;   // 0..65535
    const int b = gid >> 10;             // / D_DIM
    const int d = gid & (D_DIM - 1);     // % D_DIM
    const uint32_t base_bytes = ((uint32_t)b * (T_STEPS * D_DIM) + (uint32_t)d) * 4u;

    uint32_t voffi = base_bytes;         // running input byte offset (per-lane)
    uint32_t voffo = base_bytes;         // running output byte offset
    const uint64_t inp_u  = (uint64_t)in;
    const uint64_t outp_u = (uint64_t)out;

    float bufA[CT], bufB[CT];
    float v = 0.0f;

    ISSUE16(bufA);                                    // L(0)
    // chunk 0: newest 16 ops after L(0) = L(1) -> vmcnt(16) retires L(0)
    ISSUE16(bufB); WAITBUF(bufA, "16"); COMPUTE16(bufA);
    CHUNK_MID(bufB, bufA);                            // chunk 1
    #pragma unroll 1
    for (int c2 = 1; c2 <= 6; ++c2) {                 // chunks 2..13
        CHUNK_MID(bufA, bufB);
        CHUNK_MID(bufB, bufA);
    }
    CHUNK_MID(bufA, bufB);                            // chunk 14 (issues L(15))
    // chunk 15: newest 16 = stores of chunk 14 -> vmcnt(16) retires L(15)
    WAITBUF(bufB, "16"); COMPUTE16(bufB);
}

extern "C" void kernel_launch(void* const* d_in, const int* in_sizes, int n_in,
                              void* d_out, int out_size, void* d_ws, size_t ws_size,
                              hipStream_t stream) {
    const float* in = (const float*)d_in[0];
    float* out = (float*)d_out;
    dim3 block(TPB);
    dim3 grid((B_DIM * D_DIM) / TPB);    // 256 blocks, one 256-thread slice each
    spike_scan_kernel<<<grid, block, 0, stream>>>(in, out);
}